// Round 22
// baseline (634.683 us; speedup 1.0000x reference)
//
#include <hip/hip_runtime.h>
#include <math.h>

#define HH    256
#define NHEAD 8
#define HD    32
#define CC    128
#define RR    24
#define PP    276
#define NBLK  2
#define DFF   1024
#define MTOK  (PP*CC)   // 35328

typedef float          f32x4  __attribute__((ext_vector_type(4)));
typedef short          bf16x8 __attribute__((ext_vector_type(8)));
typedef unsigned int   u32x2  __attribute__((ext_vector_type(2)));
typedef unsigned short u16;

// native 2^x: one v_exp_f32, compiler-managed TRANS hazards
__device__ __forceinline__ float fexp2(float x) {
    return __builtin_amdgcn_exp2f(x);
}
// tanh-form GELU on native ops: gelu(x) = x*e/(e+1), e = exp2(2.88539*u),
// u = 0.7978845608*x*(1+0.044715*x^2). ~9 VALU (2 TRANS) vs ~25+ for erff.
__device__ __forceinline__ float gelu_f(float x) {
    const float u = 0.7978845608028654f * x * (1.f + 0.044715f * x * x);
    const float e = fexp2(2.885390081777927f * u);   // exp(2u)
    const float r = __builtin_amdgcn_rcpf(e + 1.f);
    return x - x * r;                                 // x * e/(e+1)
}
__device__ __forceinline__ u16 f2b(float f) {
    unsigned u = __builtin_bit_cast(unsigned, f);
    unsigned r = (u + 0x7fffu + ((u >> 16) & 1u)) >> 16;
    return (u16)r;
}
__device__ __forceinline__ float b2f(u16 b) {
    unsigned u = ((unsigned)b) << 16;
    return __builtin_bit_cast(float, u);
}
__device__ __forceinline__ unsigned cvt_pk_bf16(float lo, float hi) {
    unsigned r;
    asm("v_cvt_pk_bf16_f32 %0, %1, %2" : "=v"(r) : "v"(lo), "v"(hi));
    return r;
}
// async global->LDS, 16B per lane; LDS dest = wave-uniform base + lane*16
__device__ __forceinline__ void gload16(const void* g, void* l) {
    __builtin_amdgcn_global_load_lds(
        (const __attribute__((address_space(1))) unsigned int*)g,
        (__attribute__((address_space(3))) unsigned int*)l, 16, 0, 0);
}

// ---------------------------------------------------------------------------
// h[p,c,:] = sum_r pm[p,r] * emb[x[r,c]]   (h is bf16)
// ---------------------------------------------------------------------------
__global__ __launch_bounds__(256) void k_embed(
    const int* __restrict__ x, const float* __restrict__ pm,
    const float* __restrict__ emb, u16* __restrict__ h) {
    const int p = blockIdx.x, c = blockIdx.y, t = threadIdx.x;
    float acc = 0.f;
    for (int r = 0; r < RR; ++r) {
        float w = pm[p * RR + r];
        if (w != 0.f) {
            int tok = x[r * CC + c];
            acc += w * emb[(size_t)tok * HH + t];
        }
    }
    h[((size_t)p * CC + c) * HH + t] = f2b(acc);
}

// ---------------------------------------------------------------------------
// yb[tok] = pb2  (init for the fused head dot)
// ---------------------------------------------------------------------------
__global__ __launch_bounds__(256) void k_fill(
    float* __restrict__ y, const float* __restrict__ pb2) {
    const int i = blockIdx.x * 256 + threadIdx.x;
    if (i < MTOK) y[i] = pb2[0];
}

// ---------------------------------------------------------------------------
// LayerNorm over H=256 (bf16 in, bf16 out). Wave per row, 8 rows/block.
// ---------------------------------------------------------------------------
__global__ __launch_bounds__(256) void k_ln(
    const u16* __restrict__ in, u16* __restrict__ out,
    const float* __restrict__ g, const float* __restrict__ b) {
    const int lane = threadIdx.x & 63, wid = threadIdx.x >> 6;
    const float4 gv = *(const float4*)&g[lane * 4];
    const float4 bv = *(const float4*)&b[lane * 4];
    #pragma unroll
    for (int rr = 0; rr < 2; ++rr) {
        const int row = blockIdx.x * 8 + wid * 2 + rr;
        const ushort4 hv = *(const ushort4*)&in[(size_t)row * HH + lane * 4];
        const float v0 = b2f(hv.x), v1 = b2f(hv.y), v2 = b2f(hv.z), v3 = b2f(hv.w);
        float s  = v0 + v1 + v2 + v3;
        float s2 = v0 * v0 + v1 * v1 + v2 * v2 + v3 * v3;
        #pragma unroll
        for (int off = 32; off; off >>= 1) {
            s  += __shfl_xor(s,  off);
            s2 += __shfl_xor(s2, off);
        }
        const float mean = s * (1.f / HH);
        const float rstd = rsqrtf(s2 * (1.f / HH) - mean * mean + 1e-5f);
        u32x2 o;
        o.x = cvt_pk_bf16((v0 - mean) * rstd * gv.x + bv.x,
                          (v1 - mean) * rstd * gv.y + bv.y);
        o.y = cvt_pk_bf16((v2 - mean) * rstd * gv.z + bv.z,
                          (v3 - mean) * rstd * gv.w + bv.w);
        *(u32x2*)&out[(size_t)row * HH + lane * 4] = o;
    }
}

// ---------------------------------------------------------------------------
// Transpose + f32->bf16 (+scale): src f32 [R][Cc] -> dst bf16 [Cc][R]
// ---------------------------------------------------------------------------
__global__ __launch_bounds__(256) void k_cvtT(
    const float* __restrict__ src, u16* __restrict__ dst,
    int R, int Cc, int dstStride, float mul) {
    __shared__ float tile[32][33];
    const size_t so = (size_t)blockIdx.z * R * Cc;
    const size_t dOff = (size_t)blockIdx.z * dstStride;
    const int r0 = blockIdx.x * 32, c0 = blockIdx.y * 32;
    const int tx = threadIdx.x & 31, ty = threadIdx.x >> 5;  // 32 x 8
    #pragma unroll
    for (int i = 0; i < 4; ++i)
        tile[ty + 8 * i][tx] = src[so + (size_t)(r0 + ty + 8 * i) * Cc + c0 + tx];
    __syncthreads();
    #pragma unroll
    for (int i = 0; i < 4; ++i)
        dst[dOff + (size_t)(c0 + ty + 8 * i) * R + r0 + tx] = f2b(mul * tile[tx][ty + 8 * i]);
}

// ---------------------------------------------------------------------------
// bf16 MFMA GEMM (R14/R16-verified structure): 128x64 tile, BK=32, 3-stage
// gload_lds pipeline, counted vmcnt, setprio; LDS re-tile epilogue with
// full-line NT stores. All-bf16 I/O; DOT fuses the pw2 head reduction.
// ---------------------------------------------------------------------------
#define BM 128
#define BN 64
#define BK 32
template<bool BIAS, bool GELU, bool RES, bool STORE, bool DOT>
__global__ __launch_bounds__(256) void k_mgemm(
    const u16* __restrict__ A,   // [M][K] bf16
    const u16* __restrict__ Wt,  // [N][K] bf16 (pre-transposed)
    const float* __restrict__ bias,
    u16* __restrict__ Cb,        // [M][N] bf16 in/out
    const float* __restrict__ pw2,  // [N] dot weights (DOT)
    float* __restrict__ y,          // [M] dot accum   (DOT)
    int M, int N, int K) {
    __shared__ __align__(16) char smem[36864];     // Al 24KB + Bl 12KB; Ct 32KB overlays
    u16 (*Al)[BM * BK] = (u16(*)[BM * BK])smem;
    u16 (*Bl)[BN * BK] = (u16(*)[BN * BK])(smem + 24576);
    const int tid = threadIdx.x;
    const int wid = tid >> 6, lane = tid & 63;
    const int wr = wid >> 1, wc = wid & 1;
    const int l16 = lane & 15, lh = lane >> 4;

    const int nwg = gridDim.x;
    const int ntx = N >> 6;                        // N / BN
    const int swz = (blockIdx.x & 7) * (nwg >> 3) + (blockIdx.x >> 3);
    const int row0 = (swz / ntx) * BM, col0 = (swz % ntx) * BN;

    int rA[2], pA[2];
    #pragma unroll
    for (int i = 0; i < 2; ++i) {
        const int d = tid + i * 256;
        rA[i] = d >> 2;
        pA[i] = (d & 3) ^ ((rA[i] >> 1) & 3);
    }
    const int nB = tid >> 2;
    const int pB = (tid & 3) ^ ((nB >> 1) & 3);
    const int nt = K / BK;

    auto stage = [&](int buf, int kt) {
        #pragma unroll
        for (int i = 0; i < 2; ++i)
            gload16(A + (size_t)(row0 + rA[i]) * K + kt + pA[i] * 8,
                    (char*)&Al[buf][0] + (wid * 64 + i * 256) * 16);
        gload16(Wt + (size_t)(col0 + nB) * K + kt + pB * 8,
                (char*)&Bl[buf][0] + (wid * 64) * 16);
    };

    f32x4 acc[4][2];
    #pragma unroll
    for (int m = 0; m < 4; ++m)
        #pragma unroll
        for (int n = 0; n < 2; ++n) acc[m][n] = (f32x4){0.f, 0.f, 0.f, 0.f};

    stage(0, 0);
    stage(1, BK);
    for (int t = 0; t < nt; ++t) {
        const int cur = t % 3;
        if (t + 1 < nt) asm volatile("s_waitcnt vmcnt(3)" ::: "memory");
        else            asm volatile("s_waitcnt vmcnt(0)" ::: "memory");
        __builtin_amdgcn_s_barrier();
        __builtin_amdgcn_sched_barrier(0);
        if (t + 2 < nt) stage((t + 2) % 3, (t + 2) * BK);
        bf16x8 af[4], bfr[2];
        #pragma unroll
        for (int m = 0; m < 4; ++m) {
            const int r = wr * 64 + m * 16 + l16;
            af[m] = *(const bf16x8*)((const char*)&Al[cur][0]
                     + r * 64 + ((lh ^ ((r >> 1) & 3)) << 4));
        }
        #pragma unroll
        for (int n = 0; n < 2; ++n) {
            const int nn = wc * 32 + n * 16 + l16;
            bfr[n] = *(const bf16x8*)((const char*)&Bl[cur][0]
                     + nn * 64 + ((lh ^ ((nn >> 1) & 3)) << 4));
        }
        asm volatile("s_waitcnt lgkmcnt(0)" ::: "memory");
        __builtin_amdgcn_sched_barrier(0);
        __builtin_amdgcn_s_setprio(1);
        #pragma unroll
        for (int m = 0; m < 4; ++m)
            #pragma unroll
            for (int n = 0; n < 2; ++n)
                acc[m][n] = __builtin_amdgcn_mfma_f32_16x16x32_bf16(
                    bfr[n], af[m], acc[m][n], 0, 0, 0);
        __builtin_amdgcn_s_setprio(0);
    }

    // ---- epilogue: re-tile through LDS, then full-line NT stores / dot ----
    __syncthreads();
    char* Ct = smem;
    const int lh4 = lh * 4;
    #pragma unroll
    for (int m = 0; m < 4; ++m) {
        const int r = wr * 64 + m * 16 + l16;
        #pragma unroll
        for (int n = 0; n < 2; ++n) {
            const int c = wc * 32 + n * 16 + lh4;
            const int bo = (r * BN + c) * 4 ^ ((r & 7) << 4);
            *(f32x4*)(Ct + bo) = acc[m][n];
        }
    }
    __syncthreads();
    #pragma unroll
    for (int i = 0; i < 8; ++i) {
        const int chunk = tid + i * 256;
        const int r = chunk >> 4, c4 = (chunk & 15) * 4;
        const int bo = (r * BN + c4) * 4 ^ ((r & 7) << 4);
        f32x4 v = *(const f32x4*)(Ct + bo);
        const int colg = col0 + c4;
        const size_t off = (size_t)(row0 + r) * N + colg;
        if (BIAS) v += *(const f32x4*)&bias[colg];
        if (GELU) {
            v[0] = gelu_f(v[0]); v[1] = gelu_f(v[1]);
            v[2] = gelu_f(v[2]); v[3] = gelu_f(v[3]);
        }
        if (RES) {
            const ushort4 rv = *(const ushort4*)&Cb[off];
            v[0] += b2f(rv.x); v[1] += b2f(rv.y);
            v[2] += b2f(rv.z); v[3] += b2f(rv.w);
        }
        if (STORE) {
            u32x2 o;
            o.x = cvt_pk_bf16(v[0], v[1]);
            o.y = cvt_pk_bf16(v[2], v[3]);
            __builtin_nontemporal_store(o, (u32x2*)&Cb[off]);
        }
        if (DOT) {
            const f32x4 wv = *(const f32x4*)&pw2[colg];
            float part = v[0] * wv[0] + v[1] * wv[1] + v[2] * wv[2] + v[3] * wv[3];
            part += __shfl_xor(part, 1);
            part += __shfl_xor(part, 2);
            part += __shfl_xor(part, 4);
            part += __shfl_xor(part, 8);
            if ((tid & 15) == 0) atomicAdd(&y[row0 + r], part);
        }
    }
}

// ---------------------------------------------------------------------------
// Fused MFMA flash attention (bf16 in/out, f32 softmax state).
// R6/R9/R17-verified one-pass online softmax + shfl P-exchange; paired-u32
// V^T staging, NOW with conflict-free write order: consecutive threads
// write consecutive kp at the same LDS row (coalesced dwords) instead of
// rows 8 apart (which alias banks at dword-stride 148). Same final layout.
// Scores in log2 domain; all exps native v_exp via fexp2.
// Row: 256 thr NQT=2; col: 384 thr NQT=3.
// ---------------------------------------------------------------------------
template<int NQT>
__global__ __launch_bounds__(384) void k_fattn(
    const u16* __restrict__ qg, const u16* __restrict__ kg,
    const u16* __restrict__ vg, u16* __restrict__ og,
    int S, int base_mul, int stride, int rowH) {
    const int head = blockIdx.y;
    const int base = blockIdx.x * base_mul;
    const int tid  = threadIdx.x;
    const int w = tid >> 6, lane = tid & 63;
    const int l16 = lane & 15, lh = lane >> 4;

    __shared__ u16 Vt[32 * 296];

    const int nkt = (S + 15) >> 4;
    const int nch = (nkt + 1) >> 1;
    const int KP  = nch * 32;
    const int KPH = KP >> 1;

    unsigned* Vw = (unsigned*)Vt;
    for (int it = tid; it < KPH * 4; it += blockDim.x) {
        const int kp = it % KPH;            // consecutive threads -> consecutive kp
        const int d8 = (it / KPH) * 8;      // same row group -> coalesced banks
        const int k0 = kp * 2, k1 = k0 + 1;
        uint4 a = make_uint4(0u, 0u, 0u, 0u), b = a;
        if (k0 < S) a = *(const uint4*)(vg + (size_t)(base + k0 * stride) * rowH + head * HD + d8);
        if (k1 < S) b = *(const uint4*)(vg + (size_t)(base + k1 * stride) * rowH + head * HD + d8);
        Vw[(d8 + 0) * 148 + kp] = (a.x & 0xffffu) | (b.x << 16);
        Vw[(d8 + 1) * 148 + kp] = (a.x >> 16)     | (b.x & 0xffff0000u);
        Vw[(d8 + 2) * 148 + kp] = (a.y & 0xffffu) | (b.y << 16);
        Vw[(d8 + 3) * 148 + kp] = (a.y >> 16)     | (b.y & 0xffff0000u);
        Vw[(d8 + 4) * 148 + kp] = (a.z & 0xffffu) | (b.z << 16);
        Vw[(d8 + 5) * 148 + kp] = (a.z >> 16)     | (b.z & 0xffff0000u);
        Vw[(d8 + 6) * 148 + kp] = (a.w & 0xffffu) | (b.w << 16);
        Vw[(d8 + 7) * 148 + kp] = (a.w >> 16)     | (b.w & 0xffff0000u);
    }
    __syncthreads();

    bf16x8 qf[NQT];
    #pragma unroll
    for (int j = 0; j < NQT; ++j) {
        int qi = (w * NQT + j) * 16 + l16;
        int qc = qi < S ? qi : S - 1;
        qf[j] = *(const bf16x8*)(qg + (size_t)(base + qc * stride) * rowH + head * HD + lh * 8);
    }
    f32x4 acc[NQT][2];
    float mM[NQT], lL[NQT];
    #pragma unroll
    for (int j = 0; j < NQT; ++j) {
        acc[j][0] = (f32x4){0.f,0.f,0.f,0.f};
        acc[j][1] = (f32x4){0.f,0.f,0.f,0.f};
        mM[j] = -1e30f; lL[j] = 0.f;
    }

    auto ldK = [&](int kid) -> bf16x8 {
        int kc = kid < S ? kid : S - 1;
        return *(const bf16x8*)(kg + (size_t)(base + kc * stride) * rowH + head * HD + lh * 8);
    };
    auto ldV = [&](int ch, int dm) -> bf16x8 {
        return *(const bf16x8*)(Vt + (dm * 16 + l16) * 296 + ch * 32 + lh * 8);
    };

    bf16x8 kc0 = ldK(l16), kc1 = ldK(16 + l16);
    bf16x8 vc0 = ldV(0, 0), vc1 = ldV(0, 1);
    const int g0 = 2 * (lh & 1);
    const int src0 = l16 + 16 * g0, src1 = src0 + 16;
    const bool hiT = (lh >> 1) & 1;
    const int lh4 = lh * 4;

    for (int ch = 0; ch < nch; ++ch) {
        const int chn = (ch + 1 < nch) ? ch + 1 : ch;   // clamped prefetch
        bf16x8 kn0 = ldK(chn * 32 + l16);
        bf16x8 kn1 = ldK(chn * 32 + 16 + l16);
        bf16x8 vn0 = ldV(chn, 0);
        bf16x8 vn1 = ldV(chn, 1);
        const int kb = ch * 32;
        const bool fullv = (kb + 32 <= S);
        #pragma unroll
        for (int j = 0; j < NQT; ++j) {
            f32x4 s0 = __builtin_amdgcn_mfma_f32_16x16x32_bf16(
                kc0, qf[j], (f32x4){0.f,0.f,0.f,0.f}, 0, 0, 0);
            f32x4 s1 = __builtin_amdgcn_mfma_f32_16x16x32_bf16(
                kc1, qf[j], (f32x4){0.f,0.f,0.f,0.f}, 0, 0, 0);
            if (!fullv) {
                #pragma unroll
                for (int i = 0; i < 4; ++i) {
                    s0[i] = (kb + lh4 + i      < S) ? s0[i] : -1e30f;
                    s1[i] = (kb + 16 + lh4 + i < S) ? s1[i] : -1e30f;
                }
            }
            float mx = fmaxf(fmaxf(fmaxf(s0[0], s0[1]), fmaxf(s0[2], s0[3])),
                             fmaxf(fmaxf(s1[0], s1[1]), fmaxf(s1[2], s1[3])));
            mx = fmaxf(mx, __shfl_xor(mx, 16));
            mx = fmaxf(mx, __shfl_xor(mx, 32));
            const float mn = fmaxf(mM[j], mx);
            const float corr = fexp2(mM[j] - mn);
            mM[j] = mn;
            float p0[4], p1[4], ls = 0.f;
            #pragma unroll
            for (int i = 0; i < 4; ++i) {
                p0[i] = fexp2(s0[i] - mn); ls += p0[i];
                p1[i] = fexp2(s1[i] - mn); ls += p1[i];
            }
            lL[j] = lL[j] * corr + ls;
            acc[j][0] *= corr;
            acc[j][1] *= corr;
            const int w00 = (int)cvt_pk_bf16(p0[0], p0[1]);
            const int w01 = (int)cvt_pk_bf16(p0[2], p0[3]);
            const int w10 = (int)cvt_pk_bf16(p1[0], p1[1]);
            const int w11 = (int)cvt_pk_bf16(p1[2], p1[3]);
            uint4 W;
            { int a = __shfl(w00, src0), b = __shfl(w10, src0); W.x = (unsigned)(hiT ? b : a); }
            { int a = __shfl(w01, src0), b = __shfl(w11, src0); W.y = (unsigned)(hiT ? b : a); }
            { int a = __shfl(w00, src1), b = __shfl(w10, src1); W.z = (unsigned)(hiT ? b : a); }
            { int a = __shfl(w01, src1), b = __shfl(w11, src1); W.w = (unsigned)(hiT ? b : a); }
            const bf16x8 pw = __builtin_bit_cast(bf16x8, W);
            acc[j][0] = __builtin_amdgcn_mfma_f32_16x16x32_bf16(vc0, pw, acc[j][0], 0, 0, 0);
            acc[j][1] = __builtin_amdgcn_mfma_f32_16x16x32_bf16(vc1, pw, acc[j][1], 0, 0, 0);
        }
        kc0 = kn0; kc1 = kn1; vc0 = vn0; vc1 = vn1;
    }

    #pragma unroll
    for (int j = 0; j < NQT; ++j) {
        float lf = lL[j];
        lf += __shfl_xor(lf, 16);
        lf += __shfl_xor(lf, 32);
        const float inv = 1.f / lf;
        const int qi = (w * NQT + j) * 16 + l16;
        if (qi < S) {
            u16* dst = og + (size_t)(base + qi * stride) * HH + head * HD + lh4;
            #pragma unroll
            for (int dm = 0; dm < 2; ++dm) {
                u32x2 o2;
                o2.x = cvt_pk_bf16(acc[j][dm][0] * inv, acc[j][dm][1] * inv);
                o2.y = cvt_pk_bf16(acc[j][dm][2] * inv, acc[j][dm][3] * inv);
                *(u32x2*)(dst + dm * 16) = o2;
            }
        }
    }
}

// ---------------------------------------------------------------------------
__global__ __launch_bounds__(128) void k_head2(
    const float* __restrict__ y, const float* __restrict__ uw,
    const float* __restrict__ ub, float* __restrict__ out) {
    const int p = blockIdx.x, t = threadIdx.x;
    float s = y[(size_t)p * CC + t] * uw[t];
    #pragma unroll
    for (int off = 32; off; off >>= 1) s += __shfl_down(s, off);
    __shared__ float sm[2];
    if ((t & 63) == 0) sm[t >> 6] = s;
    __syncthreads();
    if (t == 0) out[p] = sm[0] + sm[1] + ub[0];
}

// ---------------------------------------------------------------------------
extern "C" void kernel_launch(void* const* d_in, const int* in_sizes, int n_in,
                              void* d_out, int out_size, void* d_ws, size_t ws_size,
                              hipStream_t stream) {
    (void)in_sizes; (void)n_in; (void)out_size; (void)ws_size;
    const int*   x    = (const int*)  d_in[0];
    const float* pm   = (const float*)d_in[1];
    const float* emb  = (const float*)d_in[2];
    const float* ln1g = (const float*)d_in[3];
    const float* ln1b = (const float*)d_in[4];
    const float* wqr  = (const float*)d_in[5];
    const float* wkr  = (const float*)d_in[6];
    const float* wvr  = (const float*)d_in[7];
    const float* wor  = (const float*)d_in[8];
    const float* ln2g = (const float*)d_in[9];
    const float* ln2b = (const float*)d_in[10];
    const float* wqc  = (const float*)d_in[11];
    const float* wkc  = (const float*)d_in[12];
    const float* wvc  = (const float*)d_in[13];
    const float* woc  = (const float*)d_in[14];
    const float* ln3g = (const float*)d_in[15];
    const float* ln3b = (const float*)d_in[16];
    const float* fw1  = (const float*)d_in[17];
    const float* fb1  = (const float*)d_in[18];
    const float* fw2  = (const float*)d_in[19];
    const float* fb2  = (const float*)d_in[20];
    const float* pw1  = (const float*)d_in[21];
    const float* pb1  = (const float*)d_in[22];
    const float* pw2  = (const float*)d_in[23];
    const float* pb2  = (const float*)d_in[24];
    const float* uw   = (const float*)d_in[25];
    const float* ub   = (const float*)d_in[26];
    float* out = (float*)d_out;

    // ---- workspace layout (h is bf16) ----
    char* wsp = (char*)d_ws;
    u16*   h   = (u16*)wsp;                                // 18,087,936 B
    u16*   zb  = h + (size_t)MTOK * HH;                    // 18,087,936 B
    u16*   wts = zb + (size_t)MTOK * HH;                   //  4,718,592 B
    float* yb  = (float*)((char*)wts + 4718592);           //    141,312 B
    u16*   scratch = (u16*)((char*)yb + 141312);
    u16* qkvb = scratch;                                   // [MTOK][768] bf16
    u16* bigb = scratch;                                   // [MTOK][1024] bf16, aliased

    u16* wqkvr_t = wts;                                    // 2 x [768][256]
    u16* wqkvc_t = wqkvr_t + 2 * 768 * HH;                 // 2 x [768][256]
    u16* wor_t   = wqkvc_t + 2 * 768 * HH;                 // 2 x [256][256]
    u16* woc_t   = wor_t + 2 * HH * HH;
    u16* fw1t    = woc_t + 2 * HH * HH;                    // 2 x [1024][256]
    u16* fw2t    = fw1t + 2 * HH * DFF;                    // 2 x [256][1024]
    u16* pw1t    = fw2t + 2 * HH * DFF;                    // [1024][256]

    // 1/sqrt(32) * log2(e): scores land in log2 domain for exp2 softmax
    const float qscale = 0.17677669529663687f * 1.4426950408889634f;
    const int QKVS = 768 * HH;

    k_cvtT<<<dim3(8, 8, 2),  256, 0, stream>>>(wqr, wqkvr_t,            HH, HH, QKVS, qscale);
    k_cvtT<<<dim3(8, 8, 2),  256, 0, stream>>>(wkr, wqkvr_t + 256 * HH, HH, HH, QKVS, 1.f);
    k_cvtT<<<dim3(8, 8, 2),  256, 0, stream>>>(wvr, wqkvr_t + 512 * HH, HH, HH, QKVS, 1.f);
    k_cvtT<<<dim3(8, 8, 2),  256, 0, stream>>>(wqc, wqkvc_t,            HH, HH, QKVS, qscale);
    k_cvtT<<<dim3(8, 8, 2),  256, 0, stream>>>(wkc, wqkvc_t + 256 * HH, HH, HH, QKVS, 1.f);
    k_cvtT<<<dim3(8, 8, 2),  256, 0, stream>>>(wvc, wqkvc_t + 512 * HH, HH, HH, QKVS, 1.f);
    k_cvtT<<<dim3(8, 8, 2),  256, 0, stream>>>(wor, wor_t, HH, HH, HH * HH, 1.f);
    k_cvtT<<<dim3(8, 8, 2),  256, 0, stream>>>(woc, woc_t, HH, HH, HH * HH, 1.f);
    k_cvtT<<<dim3(8, 32, 2), 256, 0, stream>>>(fw1, fw1t, HH, DFF, HH * DFF, 1.f);
    k_cvtT<<<dim3(32, 8, 2), 256, 0, stream>>>(fw2, fw2t, DFF, HH, HH * DFF, 1.f);
    k_cvtT<<<dim3(8, 32, 1), 256, 0, stream>>>(pw1, pw1t, HH, DFF, 0, 1.f);

    const int gQKV = (MTOK / BM) * (768 / BN);   // 3312
    const int gO   = (MTOK / BM) * (HH  / BN);   // 1104
    const int gUp  = (MTOK / BM) * (DFF / BN);   // 4416

    k_embed<<<dim3(PP, CC), 256, 0, stream>>>(x, pm, emb, h);

    for (int i = 0; i < NBLK; ++i) {
        // ---- row attention (along C) ----
        k_ln<<<MTOK / 8, 256, 0, stream>>>(h, zb, ln1g + i * HH, ln1b + i * HH);
        k_mgemm<false,false,false,true,false><<<gQKV, 256, 0, stream>>>(
            zb, wqkvr_t + (size_t)i * QKVS, nullptr, qkvb, nullptr, nullptr, MTOK, 768, HH);
        k_fattn<2><<<dim3(PP, NHEAD), 256, 0, stream>>>(
            qkvb, qkvb + 256, qkvb + 512, zb, CC, CC, 1, 768);
        k_mgemm<false,false,true,true,false><<<gO, 256, 0, stream>>>(
            zb, wor_t + (size_t)i * HH * HH, nullptr, h, nullptr, nullptr, MTOK, HH, HH);
        // ---- column attention (along P): 6 waves x NQT=3 ----
        k_ln<<<MTOK / 8, 256, 0, stream>>>(h, zb, ln2g + i * HH, ln2b + i * HH);
        k_mgemm<false,false,false,true,false><<<gQKV, 256, 0, stream>>>(
            zb, wqkvc_t + (size_t)i * QKVS, nullptr, qkvb, nullptr, nullptr, MTOK, 768, HH);
        k_fattn<3><<<dim3(CC, NHEAD), 384, 0, stream>>>(
            qkvb, qkvb + 256, qkvb + 512, zb, PP, 1, CC, 768);
        k_mgemm<false,false,true,true,false><<<gO, 256, 0, stream>>>(
            zb, woc_t + (size_t)i * HH * HH, nullptr, h, nullptr, nullptr, MTOK, HH, HH);
        // ---- feed-forward ----
        k_ln<<<MTOK / 8, 256, 0, stream>>>(h, zb, ln3g + i * HH, ln3b + i * HH);
        k_mgemm<true,true,false,true,false><<<gUp, 256, 0, stream>>>(
            zb, fw1t + (size_t)i * HH * DFF, fb1 + i * DFF, bigb, nullptr, nullptr, MTOK, DFF, HH);
        k_mgemm<true,false,true,true,false><<<gO, 256, 0, stream>>>(
            bigb, fw2t + (size_t)i * HH * DFF, fb2 + i * HH, h, nullptr, nullptr, MTOK, HH, DFF);
    }

    // ---- output head: fused GEMM+GELU+dot(pw2) -> yb, then reduce over C ----
    k_fill<<<(MTOK + 255) / 256, 256, 0, stream>>>(yb, pb2);
    k_mgemm<true,true,false,false,true><<<gUp, 256, 0, stream>>>(
        h, pw1t, pb1, nullptr, pw2, yb, MTOK, DFF, HH);
    k_head2<<<PP, 128, 0, stream>>>(yb, uw, ub, out);
}

// Round 23
// 627.159 us; speedup vs baseline: 1.0120x; 1.0120x over previous
//
#include <hip/hip_runtime.h>
#include <math.h>

#define HH    256
#define NHEAD 8
#define HD    32
#define CC    128
#define RR    24
#define PP    276
#define NBLK  2
#define DFF   1024
#define MTOK  (PP*CC)   // 35328

typedef float          f32x4  __attribute__((ext_vector_type(4)));
typedef short          bf16x8 __attribute__((ext_vector_type(8)));
typedef unsigned int   u32x2  __attribute__((ext_vector_type(2)));
typedef unsigned short u16;

// native 2^x: one v_exp_f32, compiler-managed TRANS hazards
__device__ __forceinline__ float fexp2(float x) {
    return __builtin_amdgcn_exp2f(x);
}
// tanh-form GELU on native ops: gelu(x) = x*e/(e+1), e = exp2(2.88539*u),
// u = 0.7978845608*x*(1+0.044715*x^2). ~9 VALU (2 TRANS) vs ~25+ for erff.
__device__ __forceinline__ float gelu_f(float x) {
    const float u = 0.7978845608028654f * x * (1.f + 0.044715f * x * x);
    const float e = fexp2(2.885390081777927f * u);   // exp(2u)
    const float r = __builtin_amdgcn_rcpf(e + 1.f);
    return x - x * r;                                 // x * e/(e+1)
}
__device__ __forceinline__ u16 f2b(float f) {
    unsigned u = __builtin_bit_cast(unsigned, f);
    unsigned r = (u + 0x7fffu + ((u >> 16) & 1u)) >> 16;
    return (u16)r;
}
__device__ __forceinline__ float b2f(u16 b) {
    unsigned u = ((unsigned)b) << 16;
    return __builtin_bit_cast(float, u);
}
__device__ __forceinline__ unsigned cvt_pk_bf16(float lo, float hi) {
    unsigned r;
    asm("v_cvt_pk_bf16_f32 %0, %1, %2" : "=v"(r) : "v"(lo), "v"(hi));
    return r;
}
// async global->LDS, 16B per lane; LDS dest = wave-uniform base + lane*16
__device__ __forceinline__ void gload16(const void* g, void* l) {
    __builtin_amdgcn_global_load_lds(
        (const __attribute__((address_space(1))) unsigned int*)g,
        (__attribute__((address_space(3))) unsigned int*)l, 16, 0, 0);
}

// ---------------------------------------------------------------------------
// h[p,c,:] = sum_r pm[p,r] * emb[x[r,c]]   (h is bf16)
// ---------------------------------------------------------------------------
__global__ __launch_bounds__(256) void k_embed(
    const int* __restrict__ x, const float* __restrict__ pm,
    const float* __restrict__ emb, u16* __restrict__ h) {
    const int p = blockIdx.x, c = blockIdx.y, t = threadIdx.x;
    float acc = 0.f;
    for (int r = 0; r < RR; ++r) {
        float w = pm[p * RR + r];
        if (w != 0.f) {
            int tok = x[r * CC + c];
            acc += w * emb[(size_t)tok * HH + t];
        }
    }
    h[((size_t)p * CC + c) * HH + t] = f2b(acc);
}

// ---------------------------------------------------------------------------
// yb[tok] = pb2  (init for the fused head dot)
// ---------------------------------------------------------------------------
__global__ __launch_bounds__(256) void k_fill(
    float* __restrict__ y, const float* __restrict__ pb2) {
    const int i = blockIdx.x * 256 + threadIdx.x;
    if (i < MTOK) y[i] = pb2[0];
}

// ---------------------------------------------------------------------------
// LayerNorm over H=256 (bf16 in, bf16 out). Wave per row, 8 rows/block.
// ---------------------------------------------------------------------------
__global__ __launch_bounds__(256) void k_ln(
    const u16* __restrict__ in, u16* __restrict__ out,
    const float* __restrict__ g, const float* __restrict__ b) {
    const int lane = threadIdx.x & 63, wid = threadIdx.x >> 6;
    const float4 gv = *(const float4*)&g[lane * 4];
    const float4 bv = *(const float4*)&b[lane * 4];
    #pragma unroll
    for (int rr = 0; rr < 2; ++rr) {
        const int row = blockIdx.x * 8 + wid * 2 + rr;
        const ushort4 hv = *(const ushort4*)&in[(size_t)row * HH + lane * 4];
        const float v0 = b2f(hv.x), v1 = b2f(hv.y), v2 = b2f(hv.z), v3 = b2f(hv.w);
        float s  = v0 + v1 + v2 + v3;
        float s2 = v0 * v0 + v1 * v1 + v2 * v2 + v3 * v3;
        #pragma unroll
        for (int off = 32; off; off >>= 1) {
            s  += __shfl_xor(s,  off);
            s2 += __shfl_xor(s2, off);
        }
        const float mean = s * (1.f / HH);
        const float rstd = rsqrtf(s2 * (1.f / HH) - mean * mean + 1e-5f);
        u32x2 o;
        o.x = cvt_pk_bf16((v0 - mean) * rstd * gv.x + bv.x,
                          (v1 - mean) * rstd * gv.y + bv.y);
        o.y = cvt_pk_bf16((v2 - mean) * rstd * gv.z + bv.z,
                          (v3 - mean) * rstd * gv.w + bv.w);
        *(u32x2*)&out[(size_t)row * HH + lane * 4] = o;
    }
}

// ---------------------------------------------------------------------------
// Transpose + f32->bf16 (+scale): src f32 [R][Cc] -> dst bf16 [Cc][R]
// ---------------------------------------------------------------------------
__global__ __launch_bounds__(256) void k_cvtT(
    const float* __restrict__ src, u16* __restrict__ dst,
    int R, int Cc, int dstStride, float mul) {
    __shared__ float tile[32][33];
    const size_t so = (size_t)blockIdx.z * R * Cc;
    const size_t dOff = (size_t)blockIdx.z * dstStride;
    const int r0 = blockIdx.x * 32, c0 = blockIdx.y * 32;
    const int tx = threadIdx.x & 31, ty = threadIdx.x >> 5;  // 32 x 8
    #pragma unroll
    for (int i = 0; i < 4; ++i)
        tile[ty + 8 * i][tx] = src[so + (size_t)(r0 + ty + 8 * i) * Cc + c0 + tx];
    __syncthreads();
    #pragma unroll
    for (int i = 0; i < 4; ++i)
        dst[dOff + (size_t)(c0 + ty + 8 * i) * R + r0 + tx] = f2b(mul * tile[tx][ty + 8 * i]);
}

// ---------------------------------------------------------------------------
// bf16 MFMA GEMM (R14/R16-verified structure): 128x64 tile, BK=32, 3-stage
// gload_lds pipeline, counted vmcnt, setprio; LDS re-tile epilogue with
// full-line NT stores. All-bf16 I/O; DOT fuses the pw2 head reduction.
// ---------------------------------------------------------------------------
#define BM 128
#define BN 64
#define BK 32
template<bool BIAS, bool GELU, bool RES, bool STORE, bool DOT>
__global__ __launch_bounds__(256) void k_mgemm(
    const u16* __restrict__ A,   // [M][K] bf16
    const u16* __restrict__ Wt,  // [N][K] bf16 (pre-transposed)
    const float* __restrict__ bias,
    u16* __restrict__ Cb,        // [M][N] bf16 in/out
    const float* __restrict__ pw2,  // [N] dot weights (DOT)
    float* __restrict__ y,          // [M] dot accum   (DOT)
    int M, int N, int K) {
    __shared__ __align__(16) char smem[36864];     // Al 24KB + Bl 12KB; Ct 32KB overlays
    u16 (*Al)[BM * BK] = (u16(*)[BM * BK])smem;
    u16 (*Bl)[BN * BK] = (u16(*)[BN * BK])(smem + 24576);
    const int tid = threadIdx.x;
    const int wid = tid >> 6, lane = tid & 63;
    const int wr = wid >> 1, wc = wid & 1;
    const int l16 = lane & 15, lh = lane >> 4;

    const int nwg = gridDim.x;
    const int ntx = N >> 6;                        // N / BN
    const int swz = (blockIdx.x & 7) * (nwg >> 3) + (blockIdx.x >> 3);
    const int row0 = (swz / ntx) * BM, col0 = (swz % ntx) * BN;

    int rA[2], pA[2];
    #pragma unroll
    for (int i = 0; i < 2; ++i) {
        const int d = tid + i * 256;
        rA[i] = d >> 2;
        pA[i] = (d & 3) ^ ((rA[i] >> 1) & 3);
    }
    const int nB = tid >> 2;
    const int pB = (tid & 3) ^ ((nB >> 1) & 3);
    const int nt = K / BK;

    auto stage = [&](int buf, int kt) {
        #pragma unroll
        for (int i = 0; i < 2; ++i)
            gload16(A + (size_t)(row0 + rA[i]) * K + kt + pA[i] * 8,
                    (char*)&Al[buf][0] + (wid * 64 + i * 256) * 16);
        gload16(Wt + (size_t)(col0 + nB) * K + kt + pB * 8,
                (char*)&Bl[buf][0] + (wid * 64) * 16);
    };

    f32x4 acc[4][2];
    #pragma unroll
    for (int m = 0; m < 4; ++m)
        #pragma unroll
        for (int n = 0; n < 2; ++n) acc[m][n] = (f32x4){0.f, 0.f, 0.f, 0.f};

    stage(0, 0);
    stage(1, BK);
    for (int t = 0; t < nt; ++t) {
        const int cur = t % 3;
        if (t + 1 < nt) asm volatile("s_waitcnt vmcnt(3)" ::: "memory");
        else            asm volatile("s_waitcnt vmcnt(0)" ::: "memory");
        __builtin_amdgcn_s_barrier();
        __builtin_amdgcn_sched_barrier(0);
        if (t + 2 < nt) stage((t + 2) % 3, (t + 2) * BK);
        bf16x8 af[4], bfr[2];
        #pragma unroll
        for (int m = 0; m < 4; ++m) {
            const int r = wr * 64 + m * 16 + l16;
            af[m] = *(const bf16x8*)((const char*)&Al[cur][0]
                     + r * 64 + ((lh ^ ((r >> 1) & 3)) << 4));
        }
        #pragma unroll
        for (int n = 0; n < 2; ++n) {
            const int nn = wc * 32 + n * 16 + l16;
            bfr[n] = *(const bf16x8*)((const char*)&Bl[cur][0]
                     + nn * 64 + ((lh ^ ((nn >> 1) & 3)) << 4));
        }
        asm volatile("s_waitcnt lgkmcnt(0)" ::: "memory");
        __builtin_amdgcn_sched_barrier(0);
        __builtin_amdgcn_s_setprio(1);
        #pragma unroll
        for (int m = 0; m < 4; ++m)
            #pragma unroll
            for (int n = 0; n < 2; ++n)
                acc[m][n] = __builtin_amdgcn_mfma_f32_16x16x32_bf16(
                    bfr[n], af[m], acc[m][n], 0, 0, 0);
        __builtin_amdgcn_s_setprio(0);
    }

    // ---- epilogue: re-tile through LDS, then full-line NT stores / dot ----
    __syncthreads();
    char* Ct = smem;
    const int lh4 = lh * 4;
    #pragma unroll
    for (int m = 0; m < 4; ++m) {
        const int r = wr * 64 + m * 16 + l16;
        #pragma unroll
        for (int n = 0; n < 2; ++n) {
            const int c = wc * 32 + n * 16 + lh4;
            const int bo = (r * BN + c) * 4 ^ ((r & 7) << 4);
            *(f32x4*)(Ct + bo) = acc[m][n];
        }
    }
    __syncthreads();
    #pragma unroll
    for (int i = 0; i < 8; ++i) {
        const int chunk = tid + i * 256;
        const int r = chunk >> 4, c4 = (chunk & 15) * 4;
        const int bo = (r * BN + c4) * 4 ^ ((r & 7) << 4);
        f32x4 v = *(const f32x4*)(Ct + bo);
        const int colg = col0 + c4;
        const size_t off = (size_t)(row0 + r) * N + colg;
        if (BIAS) v += *(const f32x4*)&bias[colg];
        if (GELU) {
            v[0] = gelu_f(v[0]); v[1] = gelu_f(v[1]);
            v[2] = gelu_f(v[2]); v[3] = gelu_f(v[3]);
        }
        if (RES) {
            const ushort4 rv = *(const ushort4*)&Cb[off];
            v[0] += b2f(rv.x); v[1] += b2f(rv.y);
            v[2] += b2f(rv.z); v[3] += b2f(rv.w);
        }
        if (STORE) {
            u32x2 o;
            o.x = cvt_pk_bf16(v[0], v[1]);
            o.y = cvt_pk_bf16(v[2], v[3]);
            __builtin_nontemporal_store(o, (u32x2*)&Cb[off]);
        }
        if (DOT) {
            const f32x4 wv = *(const f32x4*)&pw2[colg];
            float part = v[0] * wv[0] + v[1] * wv[1] + v[2] * wv[2] + v[3] * wv[3];
            part += __shfl_xor(part, 1);
            part += __shfl_xor(part, 2);
            part += __shfl_xor(part, 4);
            part += __shfl_xor(part, 8);
            if ((tid & 15) == 0) atomicAdd(&y[row0 + r], part);
        }
    }
}

// ---------------------------------------------------------------------------
// Fused MFMA flash attention (bf16 in/out, f32 softmax state).
// R6/R9/R17-verified one-pass online softmax + shfl P-exchange; paired-u32
// V^T staging. Scores in log2 domain (log2e folded into wq) -> all exps
// native v_exp via fexp2. Row: 256 thr NQT=2; col: 384 thr NQT=3.
// ---------------------------------------------------------------------------
template<int NQT>
__global__ __launch_bounds__(384) void k_fattn(
    const u16* __restrict__ qg, const u16* __restrict__ kg,
    const u16* __restrict__ vg, u16* __restrict__ og,
    int S, int base_mul, int stride, int rowH) {
    const int head = blockIdx.y;
    const int base = blockIdx.x * base_mul;
    const int tid  = threadIdx.x;
    const int w = tid >> 6, lane = tid & 63;
    const int l16 = lane & 15, lh = lane >> 4;

    __shared__ u16 Vt[32 * 296];

    const int nkt = (S + 15) >> 4;
    const int nch = (nkt + 1) >> 1;
    const int KP  = nch * 32;

    unsigned* Vw = (unsigned*)Vt;
    for (int it = tid; it < (KP >> 1) * 4; it += blockDim.x) {
        const int kp = it >> 2, d8 = (it & 3) * 8;
        const int k0 = kp * 2, k1 = k0 + 1;
        uint4 a = make_uint4(0u, 0u, 0u, 0u), b = a;
        if (k0 < S) a = *(const uint4*)(vg + (size_t)(base + k0 * stride) * rowH + head * HD + d8);
        if (k1 < S) b = *(const uint4*)(vg + (size_t)(base + k1 * stride) * rowH + head * HD + d8);
        Vw[(d8 + 0) * 148 + kp] = (a.x & 0xffffu) | (b.x << 16);
        Vw[(d8 + 1) * 148 + kp] = (a.x >> 16)     | (b.x & 0xffff0000u);
        Vw[(d8 + 2) * 148 + kp] = (a.y & 0xffffu) | (b.y << 16);
        Vw[(d8 + 3) * 148 + kp] = (a.y >> 16)     | (b.y & 0xffff0000u);
        Vw[(d8 + 4) * 148 + kp] = (a.z & 0xffffu) | (b.z << 16);
        Vw[(d8 + 5) * 148 + kp] = (a.z >> 16)     | (b.z & 0xffff0000u);
        Vw[(d8 + 6) * 148 + kp] = (a.w & 0xffffu) | (b.w << 16);
        Vw[(d8 + 7) * 148 + kp] = (a.w >> 16)     | (b.w & 0xffff0000u);
    }
    __syncthreads();

    bf16x8 qf[NQT];
    #pragma unroll
    for (int j = 0; j < NQT; ++j) {
        int qi = (w * NQT + j) * 16 + l16;
        int qc = qi < S ? qi : S - 1;
        qf[j] = *(const bf16x8*)(qg + (size_t)(base + qc * stride) * rowH + head * HD + lh * 8);
    }
    f32x4 acc[NQT][2];
    float mM[NQT], lL[NQT];
    #pragma unroll
    for (int j = 0; j < NQT; ++j) {
        acc[j][0] = (f32x4){0.f,0.f,0.f,0.f};
        acc[j][1] = (f32x4){0.f,0.f,0.f,0.f};
        mM[j] = -1e30f; lL[j] = 0.f;
    }

    auto ldK = [&](int kid) -> bf16x8 {
        int kc = kid < S ? kid : S - 1;
        return *(const bf16x8*)(kg + (size_t)(base + kc * stride) * rowH + head * HD + lh * 8);
    };
    auto ldV = [&](int ch, int dm) -> bf16x8 {
        return *(const bf16x8*)(Vt + (dm * 16 + l16) * 296 + ch * 32 + lh * 8);
    };

    bf16x8 kc0 = ldK(l16), kc1 = ldK(16 + l16);
    bf16x8 vc0 = ldV(0, 0), vc1 = ldV(0, 1);
    const int g0 = 2 * (lh & 1);
    const int src0 = l16 + 16 * g0, src1 = src0 + 16;
    const bool hiT = (lh >> 1) & 1;
    const int lh4 = lh * 4;

    for (int ch = 0; ch < nch; ++ch) {
        const int chn = (ch + 1 < nch) ? ch + 1 : ch;   // clamped prefetch
        bf16x8 kn0 = ldK(chn * 32 + l16);
        bf16x8 kn1 = ldK(chn * 32 + 16 + l16);
        bf16x8 vn0 = ldV(chn, 0);
        bf16x8 vn1 = ldV(chn, 1);
        const int kb = ch * 32;
        const bool fullv = (kb + 32 <= S);
        #pragma unroll
        for (int j = 0; j < NQT; ++j) {
            f32x4 s0 = __builtin_amdgcn_mfma_f32_16x16x32_bf16(
                kc0, qf[j], (f32x4){0.f,0.f,0.f,0.f}, 0, 0, 0);
            f32x4 s1 = __builtin_amdgcn_mfma_f32_16x16x32_bf16(
                kc1, qf[j], (f32x4){0.f,0.f,0.f,0.f}, 0, 0, 0);
            if (!fullv) {
                #pragma unroll
                for (int i = 0; i < 4; ++i) {
                    s0[i] = (kb + lh4 + i      < S) ? s0[i] : -1e30f;
                    s1[i] = (kb + 16 + lh4 + i < S) ? s1[i] : -1e30f;
                }
            }
            float mx = fmaxf(fmaxf(fmaxf(s0[0], s0[1]), fmaxf(s0[2], s0[3])),
                             fmaxf(fmaxf(s1[0], s1[1]), fmaxf(s1[2], s1[3])));
            mx = fmaxf(mx, __shfl_xor(mx, 16));
            mx = fmaxf(mx, __shfl_xor(mx, 32));
            const float mn = fmaxf(mM[j], mx);
            const float corr = fexp2(mM[j] - mn);
            mM[j] = mn;
            float p0[4], p1[4], ls = 0.f;
            #pragma unroll
            for (int i = 0; i < 4; ++i) {
                p0[i] = fexp2(s0[i] - mn); ls += p0[i];
                p1[i] = fexp2(s1[i] - mn); ls += p1[i];
            }
            lL[j] = lL[j] * corr + ls;
            acc[j][0] *= corr;
            acc[j][1] *= corr;
            const int w00 = (int)cvt_pk_bf16(p0[0], p0[1]);
            const int w01 = (int)cvt_pk_bf16(p0[2], p0[3]);
            const int w10 = (int)cvt_pk_bf16(p1[0], p1[1]);
            const int w11 = (int)cvt_pk_bf16(p1[2], p1[3]);
            uint4 W;
            { int a = __shfl(w00, src0), b = __shfl(w10, src0); W.x = (unsigned)(hiT ? b : a); }
            { int a = __shfl(w01, src0), b = __shfl(w11, src0); W.y = (unsigned)(hiT ? b : a); }
            { int a = __shfl(w00, src1), b = __shfl(w10, src1); W.z = (unsigned)(hiT ? b : a); }
            { int a = __shfl(w01, src1), b = __shfl(w11, src1); W.w = (unsigned)(hiT ? b : a); }
            const bf16x8 pw = __builtin_bit_cast(bf16x8, W);
            acc[j][0] = __builtin_amdgcn_mfma_f32_16x16x32_bf16(vc0, pw, acc[j][0], 0, 0, 0);
            acc[j][1] = __builtin_amdgcn_mfma_f32_16x16x32_bf16(vc1, pw, acc[j][1], 0, 0, 0);
        }
        kc0 = kn0; kc1 = kn1; vc0 = vn0; vc1 = vn1;
    }

    #pragma unroll
    for (int j = 0; j < NQT; ++j) {
        float lf = lL[j];
        lf += __shfl_xor(lf, 16);
        lf += __shfl_xor(lf, 32);
        const float inv = 1.f / lf;
        const int qi = (w * NQT + j) * 16 + l16;
        if (qi < S) {
            u16* dst = og + (size_t)(base + qi * stride) * HH + head * HD + lh4;
            #pragma unroll
            for (int dm = 0; dm < 2; ++dm) {
                u32x2 o2;
                o2.x = cvt_pk_bf16(acc[j][dm][0] * inv, acc[j][dm][1] * inv);
                o2.y = cvt_pk_bf16(acc[j][dm][2] * inv, acc[j][dm][3] * inv);
                *(u32x2*)(dst + dm * 16) = o2;
            }
        }
    }
}

// ---------------------------------------------------------------------------
__global__ __launch_bounds__(128) void k_head2(
    const float* __restrict__ y, const float* __restrict__ uw,
    const float* __restrict__ ub, float* __restrict__ out) {
    const int p = blockIdx.x, t = threadIdx.x;
    float s = y[(size_t)p * CC + t] * uw[t];
    #pragma unroll
    for (int off = 32; off; off >>= 1) s += __shfl_down(s, off);
    __shared__ float sm[2];
    if ((t & 63) == 0) sm[t >> 6] = s;
    __syncthreads();
    if (t == 0) out[p] = sm[0] + sm[1] + ub[0];
}

// ---------------------------------------------------------------------------
extern "C" void kernel_launch(void* const* d_in, const int* in_sizes, int n_in,
                              void* d_out, int out_size, void* d_ws, size_t ws_size,
                              hipStream_t stream) {
    (void)in_sizes; (void)n_in; (void)out_size; (void)ws_size;
    const int*   x    = (const int*)  d_in[0];
    const float* pm   = (const float*)d_in[1];
    const float* emb  = (const float*)d_in[2];
    const float* ln1g = (const float*)d_in[3];
    const float* ln1b = (const float*)d_in[4];
    const float* wqr  = (const float*)d_in[5];
    const float* wkr  = (const float*)d_in[6];
    const float* wvr  = (const float*)d_in[7];
    const float* wor  = (const float*)d_in[8];
    const float* ln2g = (const float*)d_in[9];
    const float* ln2b = (const float*)d_in[10];
    const float* wqc  = (const float*)d_in[11];
    const float* wkc  = (const float*)d_in[12];
    const float* wvc  = (const float*)d_in[13];
    const float* woc  = (const float*)d_in[14];
    const float* ln3g = (const float*)d_in[15];
    const float* ln3b = (const float*)d_in[16];
    const float* fw1  = (const float*)d_in[17];
    const float* fb1  = (const float*)d_in[18];
    const float* fw2  = (const float*)d_in[19];
    const float* fb2  = (const float*)d_in[20];
    const float* pw1  = (const float*)d_in[21];
    const float* pb1  = (const float*)d_in[22];
    const float* pw2  = (const float*)d_in[23];
    const float* pb2  = (const float*)d_in[24];
    const float* uw   = (const float*)d_in[25];
    const float* ub   = (const float*)d_in[26];
    float* out = (float*)d_out;

    // ---- workspace layout (h is bf16) ----
    char* wsp = (char*)d_ws;
    u16*   h   = (u16*)wsp;                                // 18,087,936 B
    u16*   zb  = h + (size_t)MTOK * HH;                    // 18,087,936 B
    u16*   wts = zb + (size_t)MTOK * HH;                   //  4,718,592 B
    float* yb  = (float*)((char*)wts + 4718592);           //    141,312 B
    u16*   scratch = (u16*)((char*)yb + 141312);
    u16* qkvb = scratch;                                   // [MTOK][768] bf16
    u16* bigb = scratch;                                   // [MTOK][1024] bf16, aliased

    u16* wqkvr_t = wts;                                    // 2 x [768][256]
    u16* wqkvc_t = wqkvr_t + 2 * 768 * HH;                 // 2 x [768][256]
    u16* wor_t   = wqkvc_t + 2 * 768 * HH;                 // 2 x [256][256]
    u16* woc_t   = wor_t + 2 * HH * HH;
    u16* fw1t    = woc_t + 2 * HH * HH;                    // 2 x [1024][256]
    u16* fw2t    = fw1t + 2 * HH * DFF;                    // 2 x [256][1024]
    u16* pw1t    = fw2t + 2 * HH * DFF;                    // [1024][256]

    // 1/sqrt(32) * log2(e): scores land in log2 domain for exp2 softmax
    const float qscale = 0.17677669529663687f * 1.4426950408889634f;
    const int QKVS = 768 * HH;

    k_cvtT<<<dim3(8, 8, 2),  256, 0, stream>>>(wqr, wqkvr_t,            HH, HH, QKVS, qscale);
    k_cvtT<<<dim3(8, 8, 2),  256, 0, stream>>>(wkr, wqkvr_t + 256 * HH, HH, HH, QKVS, 1.f);
    k_cvtT<<<dim3(8, 8, 2),  256, 0, stream>>>(wvr, wqkvr_t + 512 * HH, HH, HH, QKVS, 1.f);
    k_cvtT<<<dim3(8, 8, 2),  256, 0, stream>>>(wqc, wqkvc_t,            HH, HH, QKVS, qscale);
    k_cvtT<<<dim3(8, 8, 2),  256, 0, stream>>>(wkc, wqkvc_t + 256 * HH, HH, HH, QKVS, 1.f);
    k_cvtT<<<dim3(8, 8, 2),  256, 0, stream>>>(wvc, wqkvc_t + 512 * HH, HH, HH, QKVS, 1.f);
    k_cvtT<<<dim3(8, 8, 2),  256, 0, stream>>>(wor, wor_t, HH, HH, HH * HH, 1.f);
    k_cvtT<<<dim3(8, 8, 2),  256, 0, stream>>>(woc, woc_t, HH, HH, HH * HH, 1.f);
    k_cvtT<<<dim3(8, 32, 2), 256, 0, stream>>>(fw1, fw1t, HH, DFF, HH * DFF, 1.f);
    k_cvtT<<<dim3(32, 8, 2), 256, 0, stream>>>(fw2, fw2t, DFF, HH, HH * DFF, 1.f);
    k_cvtT<<<dim3(8, 32, 1), 256, 0, stream>>>(pw1, pw1t, HH, DFF, 0, 1.f);

    const int gQKV = (MTOK / BM) * (768 / BN);   // 3312
    const int gO   = (MTOK / BM) * (HH  / BN);   // 1104
    const int gUp  = (MTOK / BM) * (DFF / BN);   // 4416

    k_embed<<<dim3(PP, CC), 256, 0, stream>>>(x, pm, emb, h);

    for (int i = 0; i < NBLK; ++i) {
        // ---- row attention (along C) ----
        k_ln<<<MTOK / 8, 256, 0, stream>>>(h, zb, ln1g + i * HH, ln1b + i * HH);
        k_mgemm<false,false,false,true,false><<<gQKV, 256, 0, stream>>>(
            zb, wqkvr_t + (size_t)i * QKVS, nullptr, qkvb, nullptr, nullptr, MTOK, 768, HH);
        k_fattn<2><<<dim3(PP, NHEAD), 256, 0, stream>>>(
            qkvb, qkvb + 256, qkvb + 512, zb, CC, CC, 1, 768);
        k_mgemm<false,false,true,true,false><<<gO, 256, 0, stream>>>(
            zb, wor_t + (size_t)i * HH * HH, nullptr, h, nullptr, nullptr, MTOK, HH, HH);
        // ---- column attention (along P): 6 waves x NQT=3 ----
        k_ln<<<MTOK / 8, 256, 0, stream>>>(h, zb, ln2g + i * HH, ln2b + i * HH);
        k_mgemm<false,false,false,true,false><<<gQKV, 256, 0, stream>>>(
            zb, wqkvc_t + (size_t)i * QKVS, nullptr, qkvb, nullptr, nullptr, MTOK, 768, HH);
        k_fattn<3><<<dim3(CC, NHEAD), 384, 0, stream>>>(
            qkvb, qkvb + 256, qkvb + 512, zb, PP, 1, CC, 768);
        k_mgemm<false,false,true,true,false><<<gO, 256, 0, stream>>>(
            zb, woc_t + (size_t)i * HH * HH, nullptr, h, nullptr, nullptr, MTOK, HH, HH);
        // ---- feed-forward ----
        k_ln<<<MTOK / 8, 256, 0, stream>>>(h, zb, ln3g + i * HH, ln3b + i * HH);
        k_mgemm<true,true,false,true,false><<<gUp, 256, 0, stream>>>(
            zb, fw1t + (size_t)i * HH * DFF, fb1 + i * DFF, bigb, nullptr, nullptr, MTOK, DFF, HH);
        k_mgemm<true,false,true,true,false><<<gO, 256, 0, stream>>>(
            bigb, fw2t + (size_t)i * HH * DFF, fb2 + i * HH, h, nullptr, nullptr, MTOK, HH, DFF);
    }

    // ---- output head: fused GEMM+GELU+dot(pw2) -> yb, then reduce over C ----
    k_fill<<<(MTOK + 255) / 256, 256, 0, stream>>>(yb, pb2);
    k_mgemm<true,true,false,false,true><<<gUp, 256, 0, stream>>>(
        h, pw1t, pb1, nullptr, pw2, yb, MTOK, DFF, HH);
    k_head2<<<PP, 128, 0, stream>>>(yb, uw, ub, out);
}